// Round 6
// baseline (163.404 us; speedup 1.0000x reference)
//
#include <hip/hip_runtime.h>

#define NPTS 4096
#define DIM  256
#define CANDG 128

typedef unsigned short u16;
typedef __attribute__((ext_vector_type(8))) short bf16x8;
typedef __attribute__((ext_vector_type(4))) float f32x4;
typedef __attribute__((ext_vector_type(4))) unsigned short u16x4;

__device__ __forceinline__ float exp2fast(float x) {
  float r;
  asm("v_exp_f32 %0, %1" : "=v"(r) : "v"(x));
  return r;
}

__device__ __forceinline__ void gload_lds16(const void* g, void* l) {
  __builtin_amdgcn_global_load_lds((const __attribute__((address_space(1))) void*)g,
                                   (__attribute__((address_space(3))) void*)l, 16, 0, 0);
}

// monotonic float<->uint order mapping (for atomicMax on float values)
__device__ __forceinline__ unsigned fkey(float f) {
  unsigned b = __float_as_uint(f);
  return (b & 0x80000000u) ? ~b : (b | 0x80000000u);
}
__device__ __forceinline__ float funkey(unsigned k) {
  return __uint_as_float((k & 0x80000000u) ? (k & 0x7FFFFFFFu) : ~k);
}

// ---------- block-wide reductions (256 threads = 4 waves) ----------
__device__ __forceinline__ float blk_max(float v, float* sh) {
  #pragma unroll
  for (int off = 32; off; off >>= 1) v = fmaxf(v, __shfl_down(v, off));
  int lane = threadIdx.x & 63, w = threadIdx.x >> 6;
  __syncthreads();
  if (lane == 0) sh[w] = v;
  __syncthreads();
  return fmaxf(fmaxf(sh[0], sh[1]), fmaxf(sh[2], sh[3]));
}

__device__ __forceinline__ float blk_sum(float v, float* sh) {
  #pragma unroll
  for (int off = 32; off; off >>= 1) v += __shfl_down(v, off);
  int lane = threadIdx.x & 63, w = threadIdx.x >> 6;
  __syncthreads();
  if (lane == 0) sh[w] = v;
  __syncthreads();
  return sh[0] + sh[1] + sh[2] + sh[3];
}

// ---------- K1: bf16 round + row sumsq for all three inputs ----------
__global__ __launch_bounds__(256) void split3_kernel(
    const float* __restrict__ x, const float* __restrict__ yp, const float* __restrict__ yn,
    u16* __restrict__ xb, u16* __restrict__ ypb, u16* __restrict__ ynb,
    float* __restrict__ bbp, float* __restrict__ bbn)
{
  const float* src; u16* dst; float* bb;
  if      (blockIdx.y == 0) { src = x;  dst = xb;  bb = nullptr; }
  else if (blockIdx.y == 1) { src = yp; dst = ypb; bb = bbp; }
  else                      { src = yn; dst = ynb; bb = bbn; }

  int lane = threadIdx.x & 63;
  int wave = threadIdx.x >> 6;
  int row  = blockIdx.x * 4 + wave;
  const float4 v = *reinterpret_cast<const float4*>(src + (size_t)row * DIM + lane * 4);
  float xs[4] = {v.x, v.y, v.z, v.w};
  u16x4 h;
  float ss = 0.f;
  #pragma unroll
  for (int e = 0; e < 4; ++e) {
    unsigned b = __float_as_uint(xs[e]);
    h[e] = (u16)((b + 0x7fffu + ((b >> 16) & 1u)) >> 16);   // bf16 RTNE
    ss += xs[e] * xs[e];
  }
  *reinterpret_cast<u16x4*>(dst + (size_t)row * DIM + lane * 4) = h;
  if (bb) {
    #pragma unroll
    for (int off = 32; off; off >>= 1) ss += __shfl_down(ss, off);
    if (lane == 0) bb[row] = ss;
  }
}

// ---------- reduce_ss: accums[0] = sum(bbp) + sum(bbn) ----------
__global__ __launch_bounds__(256) void reduce_ss(
    const float* __restrict__ bbp, const float* __restrict__ bbn, float* __restrict__ accums)
{
  __shared__ float red[4];
  int tid = threadIdx.x;
  float s = 0.f;
  for (int k = tid; k < NPTS; k += 256) s += bbp[k] + bbn[k];
  s = blk_sum(s, red);
  if (tid == 0) accums[0] = s;
}

// ---------- K2: bf16 GEMM 128x128 + running-rowmax candidate emission ----------
__global__ __launch_bounds__(256) void gemm_kernel(
    const u16* __restrict__ Xb, const u16* __restrict__ Ypb, const u16* __restrict__ Ynb,
    const float* __restrict__ bbp, const float* __restrict__ bbn,
    const float* __restrict__ accums,
    unsigned* __restrict__ rowKey, int* __restrict__ ccnt, u16* __restrict__ cand)
{
  __shared__ u16 Ah[128 * 64];
  __shared__ u16 Bh[128 * 64];
  __shared__ float Mred[2][128];
  __shared__ float Mrun[128];

  const int side = blockIdx.z;
  const u16* Yb; const float* bbv;
  if (side == 0) { Yb = Ypb; bbv = bbp; }
  else           { Yb = Ynb; bbv = bbn; }
  const int zoff = side * NPTS;

  const int tid  = threadIdx.x;
  const int lane = tid & 63;
  const int wave = tid >> 6;
  const int wm = wave >> 1, wn = wave & 1;
  const int l15 = lane & 15, lhi = lane >> 4;

  const int rf = blockIdx.x * 128;   // x rows
  const int cf = blockIdx.y * 128;   // y rows (cols of S)

  // staging: LDS dest linear; global source chunk pre-swizzled with (r&7)
  const int sr = lane >> 3;          // 0..7  (== r&7)
  const int sc = lane & 7;           // physical chunk
  const int gc = (sc ^ sr) * 8;      // swizzled source element

  f32x4 acc[4][4] = {};

  #pragma unroll 1
  for (int ks = 0; ks < 4; ++ks) {
    #pragma unroll
    for (int i = 0; i < 4; ++i) {
      int r = wave * 32 + i * 8 + sr;
      gload_lds16(Xb + (size_t)(rf + r) * DIM + ks * 64 + gc, Ah + r * 64 + sc * 8);
      gload_lds16(Yb + (size_t)(cf + r) * DIM + ks * 64 + gc, Bh + r * 64 + sc * 8);
    }
    asm volatile("s_waitcnt vmcnt(0)");
    __syncthreads();

    bf16x8 a[2][4], b[2][4];
    #pragma unroll
    for (int k2 = 0; k2 < 2; ++k2) {
      #pragma unroll
      for (int mi = 0; mi < 4; ++mi) {
        int R = wm * 64 + mi * 16 + l15;
        int pc = (k2 * 4 + lhi) ^ (l15 & 7);
        a[k2][mi] = *reinterpret_cast<const bf16x8*>(Ah + R * 64 + pc * 8);
      }
      #pragma unroll
      for (int ni = 0; ni < 4; ++ni) {
        int R = wn * 64 + ni * 16 + l15;
        int pc = (k2 * 4 + lhi) ^ (l15 & 7);
        b[k2][ni] = *reinterpret_cast<const bf16x8*>(Bh + R * 64 + pc * 8);
      }
    }
    #pragma unroll
    for (int k2 = 0; k2 < 2; ++k2)
      #pragma unroll
      for (int mi = 0; mi < 4; ++mi)
        #pragma unroll
        for (int ni = 0; ni < 4; ++ni)
          acc[mi][ni] = __builtin_amdgcn_mfma_f32_16x16x32_bf16(a[k2][mi], b[k2][ni], acc[mi][ni], 0, 0, 0);
    __syncthreads();
  }

  // ---- epilogue: u = 2*acc - bb[col]; running rowmax; candidate append ----
  const float scalesq = accums[0] * (1.0f / (2.0f * NPTS * DIM)) + 1e-8f;
  const float thrP = 30.0f * scalesq * 0.2f + 2.5f * scalesq + 0.5f;

  float bbc[4];
  #pragma unroll
  for (int ni = 0; ni < 4; ++ni) bbc[ni] = bbv[cf + wn * 64 + ni * 16 + l15];

  #pragma unroll
  for (int mi = 0; mi < 4; ++mi)
    #pragma unroll
    for (int ni = 0; ni < 4; ++ni)
      #pragma unroll
      for (int r = 0; r < 4; ++r)
        acc[mi][ni][r] = 2.0f * acc[mi][ni][r] - bbc[ni];

  // per-row tile max: over ni, then over the 16 l15 lanes
  #pragma unroll
  for (int mi = 0; mi < 4; ++mi)
    #pragma unroll
    for (int r = 0; r < 4; ++r) {
      float v = fmaxf(fmaxf(acc[mi][0][r], acc[mi][1][r]),
                      fmaxf(acc[mi][2][r], acc[mi][3][r]));
      #pragma unroll
      for (int off = 1; off < 16; off <<= 1) v = fmaxf(v, __shfl_xor(v, off));
      if (l15 == 0) Mred[wn][wm * 64 + mi * 16 + lhi * 4 + r] = v;
    }
  __syncthreads();

  if (tid < 128) {
    float tmax = fmaxf(Mred[0][tid], Mred[1][tid]);
    unsigned key = fkey(tmax);
    unsigned old = atomicMax(&rowKey[zoff + rf + tid], key);
    Mrun[tid] = (key >= old) ? tmax : funkey(old);   // running lower bound of final max
  }
  __syncthreads();

  #pragma unroll
  for (int mi = 0; mi < 4; ++mi)
    #pragma unroll
    for (int r = 0; r < 4; ++r) {
      int rl = wm * 64 + mi * 16 + lhi * 4 + r;
      float cut = Mrun[rl] - thrP;
      #pragma unroll
      for (int ni = 0; ni < 4; ++ni) {
        if (acc[mi][ni][r] > cut) {
          int rowG = rf + rl;
          int j = cf + wn * 64 + ni * 16 + l15;
          int idx = atomicAdd(&ccnt[zoff + rowG], 1);
          if (idx < CANDG) cand[(size_t)(zoff + rowG) * CANDG + idx] = (u16)j;
        }
      }
    }
}

// ---------- K3: per-row exact softmax over candidate set ----------
__global__ __launch_bounds__(256) void row_kernel(
    const int* __restrict__ ccnt, const u16* __restrict__ cand,
    const float* __restrict__ bbp, const float* __restrict__ bbn,
    const float* __restrict__ x,
    const float* __restrict__ ypos, const float* __restrict__ yneg,
    const float* __restrict__ accums, float* __restrict__ parts,
    float* __restrict__ Vout)
{
  __shared__ int   jl[CANDG];
  __shared__ float ulist[CANDG];
  __shared__ float wl0[CANDG], wl1[CANDG], wl2[CANDG];
  __shared__ float red[4];

  const int tid = threadIdx.x;
  const int row = blockIdx.x;
  const int lane = tid & 63, wave = tid >> 6;

  const float scalesq = accums[0] * (1.0f / (2.0f * NPTS * DIM)) + 1e-8f;
  const float L2E = 1.4426950408889634f;
  const float c0 = L2E / (scalesq * 0.02f);
  const float c1 = L2E / (scalesq * 0.05f);
  const float c2 = L2E / (scalesq * 0.2f);

  const float4 xv = *reinterpret_cast<const float4*>(x + (size_t)row * DIM + lane * 4);

  float V0 = 0.f, V1 = 0.f, V2 = 0.f;

  for (int side = 0; side < 2; ++side) {
    const float* bb = side ? bbn : bbp;
    const float* y  = side ? yneg : ypos;
    const float sgn = side ? -1.f : 1.f;
    const int zoff = side * NPTS;

    int nc = min(ccnt[zoff + row], CANDG);

    if (tid < nc) jl[tid] = (int)cand[(size_t)(zoff + row) * CANDG + tid];
    __syncthreads();
    if (tid == 0 && nc > 1) {      // insertion sort by j for determinism
      for (int i = 1; i < nc; ++i) {
        int v = jl[i], k = i - 1;
        while (k >= 0 && jl[k] > v) { jl[k + 1] = jl[k]; --k; }
        jl[k + 1] = v;
      }
    }
    __syncthreads();

    // exact f32 dot per candidate: one wave per candidate
    for (int ci = wave; ci < nc; ci += 4) {
      int j = jl[ci];
      float4 yv = *reinterpret_cast<const float4*>(y + (size_t)j * DIM + lane * 4);
      float d = xv.x * yv.x + xv.y * yv.y + xv.z * yv.z + xv.w * yv.w;
      #pragma unroll
      for (int off = 32; off; off >>= 1) d += __shfl_down(d, off);
      if (lane == 0) ulist[ci] = 2.0f * d - bb[j];
    }
    __syncthreads();

    float um = (tid < nc) ? ulist[tid] : -3.0e38f;
    float me = blk_max(um, red);

    if (tid < nc) {
      float du = ulist[tid] - me;
      wl0[tid] = exp2fast(du * c0);
      wl1[tid] = exp2fast(du * c1);
      wl2[tid] = exp2fast(du * c2);
    }
    __syncthreads();

    float p0 = 0.f, p1 = 0.f, p2 = 0.f;
    for (int ci = 0; ci < nc; ++ci) { p0 += wl0[ci]; p1 += wl1[ci]; p2 += wl2[ci]; }
    float il0 = sgn / p0, il1 = sgn / p1, il2 = sgn / p2;

    for (int ci = 0; ci < nc; ++ci) {
      float yv = y[(size_t)jl[ci] * DIM + tid];
      V0 += wl0[ci] * il0 * yv;
      V1 += wl1[ci] * il1 * yv;
      V2 += wl2[ci] * il2 * yv;
    }
    __syncthreads();
  }

  float vr = (V0 + V1 + V2) * (1.0f / 3.0f);
  Vout[(size_t)row * DIM + tid] = vr;

  float s0 = blk_sum(V0 * V0, red);
  float s1 = blk_sum(V1 * V1, red);
  float s2 = blk_sum(V2 * V2, red);
  float sr = blk_sum(vr * vr, red);
  if (tid == 0) {
    parts[row]            = sr;
    parts[NPTS + row]     = s0;
    parts[2 * NPTS + row] = s1;
    parts[3 * NPTS + row] = s2;
  }
}

// ---------- reduce_parts ----------
__global__ __launch_bounds__(256) void reduce_parts(
    const float* __restrict__ parts, float* __restrict__ accums)
{
  __shared__ float red[4];
  int tid = threadIdx.x;
  #pragma unroll
  for (int a = 0; a < 4; ++a) {
    float s = 0.f;
    for (int k = tid; k < NPTS; k += 256) s += parts[a * NPTS + k];
    s = blk_sum(s, red);
    if (tid == 0) accums[1 + a] = s;
  }
}

// ---------- K4: finalize ----------
__global__ __launch_bounds__(256) void final_kernel(
    const float* __restrict__ accums, float* __restrict__ out)
{
  float raw  = accums[1] * (1.0f / NPTS);
  float lam2 = raw * (1.0f / DIM) + 1e-8f;
  float lam  = sqrtf(lam2);
  float inv  = 1.0f / lam;
  size_t idx = (size_t)blockIdx.x * 256 + threadIdx.x;
  out[7 + idx] *= inv;
  if (blockIdx.x == 0 && threadIdx.x == 0) {
    float drift = raw / lam2;
    out[0] = drift * (1.0f / DIM);
    out[1] = drift;
    out[2] = raw;
    out[3] = lam;
    out[4] = accums[2] * (1.0f / NPTS);
    out[5] = accums[3] * (1.0f / NPTS);
    out[6] = accums[4] * (1.0f / NPTS);
  }
}

extern "C" void kernel_launch(void* const* d_in, const int* in_sizes, int n_in,
                              void* d_out, int out_size, void* d_ws, size_t ws_size,
                              hipStream_t stream)
{
  (void)in_sizes; (void)n_in; (void)out_size; (void)ws_size;
  const float* x    = (const float*)d_in[0];
  const float* ypos = (const float*)d_in[1];
  const float* yneg = (const float*)d_in[2];
  float* out = (float*)d_out;
  char* ws = (char*)d_ws;

  // ws: accums 256B | bbp 16K | bbn 16K | parts 64K | rowKey 32K | ccnt 32K | cand 2M | xb/ypb/ynb 6M
  float*    accums = (float*)ws;
  float*    bbp    = (float*)(ws + 256);
  float*    bbn    = (float*)(ws + 16640);
  float*    parts  = (float*)(ws + 33024);
  unsigned* rowKey = (unsigned*)(ws + 98560);
  int*      ccnt   = (int*)(ws + 131328);
  u16*      cand   = (u16*)(ws + 164096);
  u16* xb  = (u16*)(ws + 164096 + 2097152);
  u16* ypb = xb + (size_t)NPTS * DIM;
  u16* ynb = xb + 2 * (size_t)NPTS * DIM;

  hipMemsetAsync(ws + 98560, 0, 65536, stream);   // rowKey + ccnt
  split3_kernel<<<dim3(NPTS / 4, 3), 256, 0, stream>>>(x, ypos, yneg, xb, ypb, ynb, bbp, bbn);
  reduce_ss<<<1, 256, 0, stream>>>(bbp, bbn, accums);
  gemm_kernel<<<dim3(32, 32, 2), 256, 0, stream>>>(xb, ypb, ynb, bbp, bbn, accums,
                                                   rowKey, ccnt, cand);
  row_kernel<<<NPTS, 256, 0, stream>>>(ccnt, cand, bbp, bbn, x, ypos, yneg,
                                       accums, parts, out + 7);
  reduce_parts<<<1, 256, 0, stream>>>(parts, accums);
  final_kernel<<<NPTS, 256, 0, stream>>>(accums, out);
}

// Round 7
// 118.955 us; speedup vs baseline: 1.3737x; 1.3737x over previous
//
#include <hip/hip_runtime.h>

#define NPTS 4096
#define DIM  256
#define TIL  64       // number of 64-wide col tiles
#define SLOTS 12      // per-(row,tile) candidate slots
#define WCAND 32      // per-row candidate cap in row_kernel

typedef unsigned short u16;
typedef unsigned long long u64;
typedef __attribute__((ext_vector_type(8))) short bf16x8;
typedef __attribute__((ext_vector_type(4))) float f32x4;
typedef __attribute__((ext_vector_type(4))) unsigned short u16x4;

__device__ __forceinline__ float exp2fast(float x) {
  float r;
  asm("v_exp_f32 %0, %1" : "=v"(r) : "v"(x));
  return r;
}

__device__ __forceinline__ void gload_lds16(const void* g, void* l) {
  __builtin_amdgcn_global_load_lds((const __attribute__((address_space(1))) void*)g,
                                   (__attribute__((address_space(3))) void*)l, 16, 0, 0);
}

__device__ __forceinline__ float blk_sum(float v, float* sh) {
  #pragma unroll
  for (int off = 32; off; off >>= 1) v += __shfl_down(v, off);
  int lane = threadIdx.x & 63, w = threadIdx.x >> 6;
  __syncthreads();
  if (lane == 0) sh[w] = v;
  __syncthreads();
  return sh[0] + sh[1] + sh[2] + sh[3];
}

// ---------- K1: bf16 round + row sumsq for all three inputs ----------
__global__ __launch_bounds__(256) void split3_kernel(
    const float* __restrict__ x, const float* __restrict__ yp, const float* __restrict__ yn,
    u16* __restrict__ xb, u16* __restrict__ ypb, u16* __restrict__ ynb,
    float* __restrict__ bbp, float* __restrict__ bbn)
{
  const float* src; u16* dst; float* bb;
  if      (blockIdx.y == 0) { src = x;  dst = xb;  bb = nullptr; }
  else if (blockIdx.y == 1) { src = yp; dst = ypb; bb = bbp; }
  else                      { src = yn; dst = ynb; bb = bbn; }

  int lane = threadIdx.x & 63;
  int wave = threadIdx.x >> 6;
  int row  = blockIdx.x * 4 + wave;
  const float4 v = *reinterpret_cast<const float4*>(src + (size_t)row * DIM + lane * 4);
  float xs[4] = {v.x, v.y, v.z, v.w};
  u16x4 h;
  float ss = 0.f;
  #pragma unroll
  for (int e = 0; e < 4; ++e) {
    unsigned b = __float_as_uint(xs[e]);
    h[e] = (u16)((b + 0x7fffu + ((b >> 16) & 1u)) >> 16);   // bf16 RTNE
    ss += xs[e] * xs[e];
  }
  *reinterpret_cast<u16x4*>(dst + (size_t)row * DIM + lane * 4) = h;
  if (bb) {
    #pragma unroll
    for (int off = 32; off; off >>= 1) ss += __shfl_down(ss, off);
    if (lane == 0) bb[row] = ss;
  }
}

// ---------- reduce_ss: accums[0] = sum(bbp) + sum(bbn) ----------
__global__ __launch_bounds__(256) void reduce_ss(
    const float* __restrict__ bbp, const float* __restrict__ bbn, float* __restrict__ accums)
{
  __shared__ float red[4];
  int tid = threadIdx.x;
  float s = 0.f;
  for (int k = tid; k < NPTS; k += 256) s += bbp[k] + bbn[k];
  s = blk_sum(s, red);
  if (tid == 0) accums[0] = s;
}

// ---------- K2: bf16 GEMM 128x128 + ballot-compacted per-tile candidate emission ----------
// No global atomics. Each (row, 64-col tile) is owned by exactly one wave.
__global__ __launch_bounds__(256) void gemm_kernel(
    const u16* __restrict__ Xb, const u16* __restrict__ Ypb, const u16* __restrict__ Ynb,
    const float* __restrict__ bbp, const float* __restrict__ bbn,
    const float* __restrict__ accums,
    float* __restrict__ M, unsigned* __restrict__ cnt, unsigned* __restrict__ cand)
{
  __shared__ u16 Ah[128 * 64];
  __shared__ u16 Bh[128 * 64];

  const int side = blockIdx.z;
  const u16* Yb = side ? Ynb : Ypb;
  const float* bbv = side ? bbn : bbp;

  const int tid  = threadIdx.x;
  const int lane = tid & 63;
  const int wave = tid >> 6;
  const int wm = wave >> 1, wn = wave & 1;
  const int l15 = lane & 15, lhi = lane >> 4;

  const int rf = blockIdx.x * 128;   // x rows
  const int cf = blockIdx.y * 128;   // y rows (cols of S)
  const int til = blockIdx.y * 2 + wn;

  // staging: LDS dest linear; global source chunk pre-swizzled with (r&7)
  const int sr = lane >> 3;          // 0..7  (== r&7)
  const int sc = lane & 7;           // physical chunk
  const int gc = (sc ^ sr) * 8;      // swizzled source element

  f32x4 acc[4][4] = {};

  #pragma unroll 1
  for (int ks = 0; ks < 4; ++ks) {
    #pragma unroll
    for (int i = 0; i < 4; ++i) {
      int r = wave * 32 + i * 8 + sr;
      gload_lds16(Xb + (size_t)(rf + r) * DIM + ks * 64 + gc, Ah + r * 64 + sc * 8);
      gload_lds16(Yb + (size_t)(cf + r) * DIM + ks * 64 + gc, Bh + r * 64 + sc * 8);
    }
    asm volatile("s_waitcnt vmcnt(0)");
    __syncthreads();

    bf16x8 a[2][4], b[2][4];
    #pragma unroll
    for (int k2 = 0; k2 < 2; ++k2) {
      #pragma unroll
      for (int mi = 0; mi < 4; ++mi) {
        int R = wm * 64 + mi * 16 + l15;
        int pc = (k2 * 4 + lhi) ^ (l15 & 7);
        a[k2][mi] = *reinterpret_cast<const bf16x8*>(Ah + R * 64 + pc * 8);
      }
      #pragma unroll
      for (int ni = 0; ni < 4; ++ni) {
        int R = wn * 64 + ni * 16 + l15;
        int pc = (k2 * 4 + lhi) ^ (l15 & 7);
        b[k2][ni] = *reinterpret_cast<const bf16x8*>(Bh + R * 64 + pc * 8);
      }
    }
    #pragma unroll
    for (int k2 = 0; k2 < 2; ++k2)
      #pragma unroll
      for (int mi = 0; mi < 4; ++mi)
        #pragma unroll
        for (int ni = 0; ni < 4; ++ni)
          acc[mi][ni] = __builtin_amdgcn_mfma_f32_16x16x32_bf16(a[k2][mi], b[k2][ni], acc[mi][ni], 0, 0, 0);
    __syncthreads();
  }

  // ---- epilogue: u = 2*acc - bb[col]; per-(row,tile) max + ballot compaction ----
  const float scalesq = accums[0] * (1.0f / (2.0f * NPTS * DIM)) + 1e-8f;
  const float thrP = 30.0f * scalesq * 0.2f + 2.5f * scalesq + 0.5f;

  float bbc[4];
  #pragma unroll
  for (int ni = 0; ni < 4; ++ni) bbc[ni] = bbv[cf + wn * 64 + ni * 16 + l15];

  const unsigned lmask = (1u << l15) - 1;
  const size_t cb0 = ((size_t)side * TIL + til) * NPTS;

  #pragma unroll
  for (int mi = 0; mi < 4; ++mi)
    #pragma unroll
    for (int r = 0; r < 4; ++r) {
      float uv[4];
      float mx = -3.0e38f;
      #pragma unroll
      for (int ni = 0; ni < 4; ++ni) {
        uv[ni] = 2.0f * acc[mi][ni][r] - bbc[ni];
        mx = fmaxf(mx, uv[ni]);
      }
      #pragma unroll
      for (int off = 1; off < 16; off <<= 1) mx = fmaxf(mx, __shfl_xor(mx, off));

      const int rl = wm * 64 + mi * 16 + lhi * 4 + r;
      const int rowG = rf + rl;
      const float cut = mx - thrP;
      unsigned base = 0;
      #pragma unroll
      for (int ni = 0; ni < 4; ++ni) {
        bool keep = uv[ni] > cut;
        u64 bal = __ballot(keep);
        unsigned slice = (unsigned)((bal >> (lhi * 16)) & 0xFFFFull);
        if (keep) {
          unsigned slot = base + __popc(slice & lmask);
          if (slot < SLOTS) {
            unsigned short uh = __builtin_bit_cast(unsigned short, (_Float16)uv[ni]);
            unsigned j = (unsigned)(cf + wn * 64 + ni * 16 + l15);
            cand[(cb0 + rowG) * SLOTS + slot] = ((unsigned)uh << 16) | j;
          }
        }
        base += __popc(slice);
      }
      if (l15 == 0) {
        M[((size_t)side * NPTS + rowG) * TIL + til] = mx;
        cnt[cb0 + rowG] = base;
      }
    }
}

// ---------- K3: wave-per-row candidate softmax (no barriers, no sort) ----------
__global__ __launch_bounds__(256) void row_kernel(
    const float* __restrict__ M, const unsigned* __restrict__ cnt,
    const unsigned* __restrict__ cand,
    const float* __restrict__ bbp, const float* __restrict__ bbn,
    const float* __restrict__ x,
    const float* __restrict__ ypos, const float* __restrict__ yneg,
    const float* __restrict__ accums, float* __restrict__ parts,
    float* __restrict__ Vout)
{
  __shared__ unsigned cl[4][WCAND];
  __shared__ float    ul[4][WCAND];

  const int tid  = threadIdx.x;
  const int lane = tid & 63;
  const int w    = tid >> 6;
  const int row  = blockIdx.x * 4 + w;

  const float scalesq = accums[0] * (1.0f / (2.0f * NPTS * DIM)) + 1e-8f;
  const float L2E = 1.4426950408889634f;
  const float c0 = L2E / (scalesq * 0.02f);
  const float c1 = L2E / (scalesq * 0.05f);
  const float c2 = L2E / (scalesq * 0.2f);
  const float thrP = 30.0f * scalesq * 0.2f + 2.5f * scalesq + 0.5f;

  const f32x4 xv = *reinterpret_cast<const f32x4*>(x + (size_t)row * DIM + lane * 4);

  f32x4 V0 = {0,0,0,0}, V1 = {0,0,0,0}, V2 = {0,0,0,0};

  for (int side = 0; side < 2; ++side) {
    const float* bb = side ? bbn : bbp;
    const float* y  = side ? yneg : ypos;
    const float sgn = side ? -1.f : 1.f;

    // global row max from 64 tile maxes (one per lane)
    float Mv = M[((size_t)side * NPTS + row) * TIL + lane];
    float g = Mv;
    #pragma unroll
    for (int off = 32; off; off >>= 1) g = fmaxf(g, __shfl_xor(g, off));
    const float cut = g - thrP;

    // gather candidates from kept tiles (deterministic ballot compaction)
    u64 mm = __ballot(Mv > cut);
    int nc = 0;
    while (mm) {
      int t = __ffsll((long long)mm) - 1;
      mm &= mm - 1;
      size_t cb = ((size_t)side * TIL + t) * NPTS + row;
      unsigned c = cnt[cb];
      c = c < SLOTS ? c : SLOTS;
      bool k2 = false;
      unsigned e = 0;
      if (lane < (int)c) {
        e = cand[cb * SLOTS + lane];
        _Float16 h = __builtin_bit_cast(_Float16, (unsigned short)(e >> 16));
        k2 = ((float)h > cut);
      }
      u64 b2 = __ballot(k2);
      int rank = __popcll(b2 & ((1ull << lane) - 1ull));
      if (k2 && nc + rank < WCAND) cl[w][nc + rank] = e;
      nc += __popcll(b2);
    }
    nc = nc < WCAND ? nc : WCAND;

    // exact f32 dots for candidates
    for (int ci = 0; ci < nc; ++ci) {
      int j = cl[w][ci] & 0xFFFF;
      f32x4 yv = *reinterpret_cast<const f32x4*>(y + (size_t)j * DIM + lane * 4);
      float d = xv[0]*yv[0] + xv[1]*yv[1] + xv[2]*yv[2] + xv[3]*yv[3];
      #pragma unroll
      for (int off = 32; off; off >>= 1) d += __shfl_xor(d, off);
      float bbj = bb[j];
      if (lane == 0) ul[w][ci] = 2.0f * d - bbj;
    }

    // softmax over candidates (all lanes redundantly; nc is small)
    float me = -3.0e38f;
    for (int ci = 0; ci < nc; ++ci) me = fmaxf(me, ul[w][ci]);
    float p0 = 0.f, p1 = 0.f, p2 = 0.f;
    for (int ci = 0; ci < nc; ++ci) {
      float du = ul[w][ci] - me;
      p0 += exp2fast(du * c0);
      p1 += exp2fast(du * c1);
      p2 += exp2fast(du * c2);
    }
    float il0 = sgn / p0, il1 = sgn / p1, il2 = sgn / p2;

    // V accumulation: 4 dims per lane
    for (int ci = 0; ci < nc; ++ci) {
      int j = cl[w][ci] & 0xFFFF;
      float du = ul[w][ci] - me;
      float w0 = exp2fast(du * c0) * il0;
      float w1 = exp2fast(du * c1) * il1;
      float w2 = exp2fast(du * c2) * il2;
      f32x4 yv = *reinterpret_cast<const f32x4*>(y + (size_t)j * DIM + lane * 4);
      V0 += w0 * yv;
      V1 += w1 * yv;
      V2 += w2 * yv;
    }
  }

  f32x4 vr = (V0 + V1 + V2) * (1.0f / 3.0f);
  *reinterpret_cast<f32x4*>(Vout + (size_t)row * DIM + lane * 4) = vr;

  float s0 = V0[0]*V0[0] + V0[1]*V0[1] + V0[2]*V0[2] + V0[3]*V0[3];
  float s1 = V1[0]*V1[0] + V1[1]*V1[1] + V1[2]*V1[2] + V1[3]*V1[3];
  float s2 = V2[0]*V2[0] + V2[1]*V2[1] + V2[2]*V2[2] + V2[3]*V2[3];
  float sr = vr[0]*vr[0] + vr[1]*vr[1] + vr[2]*vr[2] + vr[3]*vr[3];
  #pragma unroll
  for (int off = 32; off; off >>= 1) {
    s0 += __shfl_xor(s0, off);
    s1 += __shfl_xor(s1, off);
    s2 += __shfl_xor(s2, off);
    sr += __shfl_xor(sr, off);
  }
  if (lane == 0) {
    parts[row]            = sr;
    parts[NPTS + row]     = s0;
    parts[2 * NPTS + row] = s1;
    parts[3 * NPTS + row] = s2;
  }
}

// ---------- reduce_parts ----------
__global__ __launch_bounds__(256) void reduce_parts(
    const float* __restrict__ parts, float* __restrict__ accums)
{
  __shared__ float red[4];
  int tid = threadIdx.x;
  #pragma unroll
  for (int a = 0; a < 4; ++a) {
    float s = 0.f;
    for (int k = tid; k < NPTS; k += 256) s += parts[a * NPTS + k];
    s = blk_sum(s, red);
    if (tid == 0) accums[1 + a] = s;
  }
}

// ---------- K4: finalize ----------
__global__ __launch_bounds__(256) void final_kernel(
    const float* __restrict__ accums, float* __restrict__ out)
{
  float raw  = accums[1] * (1.0f / NPTS);
  float lam2 = raw * (1.0f / DIM) + 1e-8f;
  float lam  = sqrtf(lam2);
  float inv  = 1.0f / lam;
  size_t idx = (size_t)blockIdx.x * 256 + threadIdx.x;
  out[7 + idx] *= inv;
  if (blockIdx.x == 0 && threadIdx.x == 0) {
    float drift = raw / lam2;
    out[0] = drift * (1.0f / DIM);
    out[1] = drift;
    out[2] = raw;
    out[3] = lam;
    out[4] = accums[2] * (1.0f / NPTS);
    out[5] = accums[3] * (1.0f / NPTS);
    out[6] = accums[4] * (1.0f / NPTS);
  }
}

extern "C" void kernel_launch(void* const* d_in, const int* in_sizes, int n_in,
                              void* d_out, int out_size, void* d_ws, size_t ws_size,
                              hipStream_t stream)
{
  (void)in_sizes; (void)n_in; (void)out_size; (void)ws_size;
  const float* x    = (const float*)d_in[0];
  const float* ypos = (const float*)d_in[1];
  const float* yneg = (const float*)d_in[2];
  float* out = (float*)d_out;
  char* ws = (char*)d_ws;

  // ws layout (all cnt/cand slots are fully rewritten each launch; no zeroing needed):
  // accums 256B | bbp 16K | bbn 16K | parts 64K | M 2M | cnt 2M | cand 25M | xb/ypb/ynb 6M
  float*    accums = (float*)ws;
  float*    bbp    = (float*)(ws + 256);
  float*    bbn    = (float*)(ws + 16640);
  float*    parts  = (float*)(ws + 33024);
  float*    M      = (float*)(ws + 98560);
  unsigned* cnt    = (unsigned*)(ws + 98560 + 2097152);
  unsigned* cand   = (unsigned*)(ws + 98560 + 2 * 2097152);
  u16* xb  = (u16*)(ws + 98560 + 2 * 2097152 + (size_t)2 * TIL * NPTS * SLOTS * 4);
  u16* ypb = xb + (size_t)NPTS * DIM;
  u16* ynb = xb + 2 * (size_t)NPTS * DIM;

  split3_kernel<<<dim3(NPTS / 4, 3), 256, 0, stream>>>(x, ypos, yneg, xb, ypb, ynb, bbp, bbn);
  reduce_ss<<<1, 256, 0, stream>>>(bbp, bbn, accums);
  gemm_kernel<<<dim3(32, 32, 2), 256, 0, stream>>>(xb, ypb, ynb, bbp, bbn, accums,
                                                   M, cnt, cand);
  row_kernel<<<NPTS / 4, 256, 0, stream>>>(M, cnt, cand, bbp, bbn, x, ypos, yneg,
                                           accums, parts, out + 7);
  reduce_parts<<<1, 256, 0, stream>>>(parts, accums);
  final_kernel<<<NPTS, 256, 0, stream>>>(accums, out);
}

// Round 8
// 106.813 us; speedup vs baseline: 1.5298x; 1.1137x over previous
//
#include <hip/hip_runtime.h>

#define NPTS 4096
#define DIM  256
#define TIL  64       // number of 64-wide col tiles
#define SLOTS 12      // per-(row,tile) candidate slots
#define WCAND 32      // per-row candidate cap in row_kernel

typedef unsigned short u16;
typedef unsigned long long u64;
typedef __attribute__((ext_vector_type(8))) short bf16x8;
typedef __attribute__((ext_vector_type(4))) float f32x4;
typedef __attribute__((ext_vector_type(4))) unsigned short u16x4;

__device__ __forceinline__ float exp2fast(float x) {
  float r;
  asm("v_exp_f32 %0, %1" : "=v"(r) : "v"(x));
  return r;
}

__device__ __forceinline__ void gload_lds16(const void* g, void* l) {
  __builtin_amdgcn_global_load_lds((const __attribute__((address_space(1))) void*)g,
                                   (__attribute__((address_space(3))) void*)l, 16, 0, 0);
}

__device__ __forceinline__ float blk_sum(float v, float* sh) {
  #pragma unroll
  for (int off = 32; off; off >>= 1) v += __shfl_down(v, off);
  int lane = threadIdx.x & 63, w = threadIdx.x >> 6;
  __syncthreads();
  if (lane == 0) sh[w] = v;
  __syncthreads();
  return sh[0] + sh[1] + sh[2] + sh[3];
}

// ---------- K1: bf16 round + row sumsq for all three inputs ----------
__global__ __launch_bounds__(256) void split3_kernel(
    const float* __restrict__ x, const float* __restrict__ yp, const float* __restrict__ yn,
    u16* __restrict__ xb, u16* __restrict__ ypb, u16* __restrict__ ynb,
    float* __restrict__ bbp, float* __restrict__ bbn)
{
  const float* src; u16* dst; float* bb;
  if      (blockIdx.y == 0) { src = x;  dst = xb;  bb = nullptr; }
  else if (blockIdx.y == 1) { src = yp; dst = ypb; bb = bbp; }
  else                      { src = yn; dst = ynb; bb = bbn; }

  int lane = threadIdx.x & 63;
  int wave = threadIdx.x >> 6;
  int row  = blockIdx.x * 4 + wave;
  const float4 v = *reinterpret_cast<const float4*>(src + (size_t)row * DIM + lane * 4);
  float xs[4] = {v.x, v.y, v.z, v.w};
  u16x4 h;
  float ss = 0.f;
  #pragma unroll
  for (int e = 0; e < 4; ++e) {
    unsigned b = __float_as_uint(xs[e]);
    h[e] = (u16)((b + 0x7fffu + ((b >> 16) & 1u)) >> 16);   // bf16 RTNE
    ss += xs[e] * xs[e];
  }
  *reinterpret_cast<u16x4*>(dst + (size_t)row * DIM + lane * 4) = h;
  if (bb) {
    #pragma unroll
    for (int off = 32; off; off >>= 1) ss += __shfl_down(ss, off);
    if (lane == 0) bb[row] = ss;
  }
}

// ---------- reduce_ss: accums[0] = sum(bbp) + sum(bbn) ----------
__global__ __launch_bounds__(256) void reduce_ss(
    const float* __restrict__ bbp, const float* __restrict__ bbn, float* __restrict__ accums)
{
  __shared__ float red[4];
  int tid = threadIdx.x;
  float s = 0.f;
  for (int k = tid; k < NPTS; k += 256) s += bbp[k] + bbn[k];
  s = blk_sum(s, red);
  if (tid == 0) accums[0] = s;
}

// ---------- K2: bf16 GEMM 128x128, double-buffered LDS, candidate emission ----------
__global__ __launch_bounds__(256) void gemm_kernel(
    const u16* __restrict__ Xb, const u16* __restrict__ Ypb, const u16* __restrict__ Ynb,
    const float* __restrict__ bbp, const float* __restrict__ bbn,
    const float* __restrict__ accums,
    float* __restrict__ M, unsigned* __restrict__ cnt, unsigned* __restrict__ cand)
{
  __shared__ u16 Ah[2][128 * 64];
  __shared__ u16 Bh[2][128 * 64];

  const int side = blockIdx.z;
  const u16* Yb = side ? Ynb : Ypb;
  const float* bbv = side ? bbn : bbp;

  const int tid  = threadIdx.x;
  const int lane = tid & 63;
  const int wave = tid >> 6;
  const int wm = wave >> 1, wn = wave & 1;
  const int l15 = lane & 15, lhi = lane >> 4;

  const int rf = blockIdx.x * 128;   // x rows
  const int cf = blockIdx.y * 128;   // y rows (cols of S)
  const int til = blockIdx.y * 2 + wn;

  // staging: LDS dest linear; global source chunk pre-swizzled with (r&7)
  const int sr = lane >> 3;          // 0..7  (== r&7)
  const int sc = lane & 7;           // physical chunk
  const int gc = (sc ^ sr) * 8;      // swizzled source element

  f32x4 acc[4][4] = {};

  // prologue: stage ks=0 into buffer 0
  #pragma unroll
  for (int i = 0; i < 4; ++i) {
    int r = wave * 32 + i * 8 + sr;
    gload_lds16(Xb + (size_t)(rf + r) * DIM + 0 * 64 + gc, Ah[0] + r * 64 + sc * 8);
    gload_lds16(Yb + (size_t)(cf + r) * DIM + 0 * 64 + gc, Bh[0] + r * 64 + sc * 8);
  }

  #pragma unroll
  for (int ks = 0; ks < 4; ++ks) {
    const int cur = ks & 1;
    asm volatile("s_waitcnt vmcnt(0)");   // current buffer's loads landed (overlapped by prev MFMA)
    __syncthreads();

    if (ks < 3) {
      #pragma unroll
      for (int i = 0; i < 4; ++i) {
        int r = wave * 32 + i * 8 + sr;
        gload_lds16(Xb + (size_t)(rf + r) * DIM + (ks + 1) * 64 + gc, Ah[cur ^ 1] + r * 64 + sc * 8);
        gload_lds16(Yb + (size_t)(cf + r) * DIM + (ks + 1) * 64 + gc, Bh[cur ^ 1] + r * 64 + sc * 8);
      }
    }

    bf16x8 a[2][4], b[2][4];
    #pragma unroll
    for (int k2 = 0; k2 < 2; ++k2) {
      #pragma unroll
      for (int mi = 0; mi < 4; ++mi) {
        int R = wm * 64 + mi * 16 + l15;
        int pc = (k2 * 4 + lhi) ^ (l15 & 7);
        a[k2][mi] = *reinterpret_cast<const bf16x8*>(Ah[cur] + R * 64 + pc * 8);
      }
      #pragma unroll
      for (int ni = 0; ni < 4; ++ni) {
        int R = wn * 64 + ni * 16 + l15;
        int pc = (k2 * 4 + lhi) ^ (l15 & 7);
        b[k2][ni] = *reinterpret_cast<const bf16x8*>(Bh[cur] + R * 64 + pc * 8);
      }
    }
    #pragma unroll
    for (int k2 = 0; k2 < 2; ++k2)
      #pragma unroll
      for (int mi = 0; mi < 4; ++mi)
        #pragma unroll
        for (int ni = 0; ni < 4; ++ni)
          acc[mi][ni] = __builtin_amdgcn_mfma_f32_16x16x32_bf16(a[k2][mi], b[k2][ni], acc[mi][ni], 0, 0, 0);
  }

  // ---- epilogue: u = 2*acc - bb[col]; per-(row,tile) max + ballot compaction ----
  const float scalesq = accums[0] * (1.0f / (2.0f * NPTS * DIM)) + 1e-8f;
  const float thrP = 30.0f * scalesq * 0.2f + 2.5f * scalesq + 0.5f;

  float bbc[4];
  #pragma unroll
  for (int ni = 0; ni < 4; ++ni) bbc[ni] = bbv[cf + wn * 64 + ni * 16 + l15];

  const unsigned lmask = (1u << l15) - 1;
  const size_t cb0 = ((size_t)side * TIL + til) * NPTS;

  #pragma unroll
  for (int mi = 0; mi < 4; ++mi)
    #pragma unroll
    for (int r = 0; r < 4; ++r) {
      float uv[4];
      float mx = -3.0e38f;
      #pragma unroll
      for (int ni = 0; ni < 4; ++ni) {
        uv[ni] = 2.0f * acc[mi][ni][r] - bbc[ni];
        mx = fmaxf(mx, uv[ni]);
      }
      #pragma unroll
      for (int off = 1; off < 16; off <<= 1) mx = fmaxf(mx, __shfl_xor(mx, off));

      const int rl = wm * 64 + mi * 16 + lhi * 4 + r;
      const int rowG = rf + rl;
      const float cut = mx - thrP;
      unsigned base = 0;
      #pragma unroll
      for (int ni = 0; ni < 4; ++ni) {
        bool keep = uv[ni] > cut;
        u64 bal = __ballot(keep);
        unsigned slice = (unsigned)((bal >> (lhi * 16)) & 0xFFFFull);
        if (keep) {
          unsigned slot = base + __popc(slice & lmask);
          if (slot < SLOTS) {
            unsigned j = (unsigned)(cf + wn * 64 + ni * 16 + l15);
            cand[(cb0 + rowG) * SLOTS + slot] = j;
          }
        }
        base += __popc(slice);
      }
      if (l15 == 0) {
        M[((size_t)side * NPTS + rowG) * TIL + til] = mx;
        cnt[cb0 + rowG] = base;
      }
    }
}

// ---------- K3: wave-per-row; parallel tile harvest + register candidates ----------
__global__ __launch_bounds__(256) void row_kernel(
    const float* __restrict__ M, const unsigned* __restrict__ cnt,
    const unsigned* __restrict__ cand,
    const float* __restrict__ bbp, const float* __restrict__ bbn,
    const float* __restrict__ x,
    const float* __restrict__ ypos, const float* __restrict__ yneg,
    const float* __restrict__ accums, float* __restrict__ parts,
    float* __restrict__ Vout)
{
  __shared__ unsigned cl[4][WCAND];

  const int tid  = threadIdx.x;
  const int lane = tid & 63;
  const int w    = tid >> 6;
  const int row  = blockIdx.x * 4 + w;

  const float scalesq = accums[0] * (1.0f / (2.0f * NPTS * DIM)) + 1e-8f;
  const float L2E = 1.4426950408889634f;
  const float c0 = L2E / (scalesq * 0.02f);
  const float c1 = L2E / (scalesq * 0.05f);
  const float c2 = L2E / (scalesq * 0.2f);
  const float thrP = 30.0f * scalesq * 0.2f + 2.5f * scalesq + 0.5f;

  const f32x4 xv = *reinterpret_cast<const f32x4*>(x + (size_t)row * DIM + lane * 4);

  f32x4 V0 = {0,0,0,0}, V1 = {0,0,0,0}, V2 = {0,0,0,0};

  for (int side = 0; side < 2; ++side) {
    const float* bb = side ? bbn : bbp;
    const float* y  = side ? yneg : ypos;
    const float sgn = side ? -1.f : 1.f;

    // lane t owns tile t: global row max + parallel cnt loads
    float Mv = M[((size_t)side * NPTS + row) * TIL + lane];
    float g = Mv;
    #pragma unroll
    for (int off = 32; off; off >>= 1) g = fmaxf(g, __shfl_xor(g, off));
    const float cut = g - thrP;

    size_t cb = ((size_t)side * TIL + lane) * NPTS + row;
    unsigned c = 0;
    if (Mv > cut) {
      c = cnt[cb];
      c = c < SLOTS ? c : SLOTS;
    }
    // exclusive prefix sum over lanes
    unsigned pfx = c;
    #pragma unroll
    for (int off = 1; off < 64; off <<= 1) {
      unsigned t = __shfl_up(pfx, off);
      if (lane >= off) pfx += t;
    }
    unsigned base = pfx - c;
    int nc = __shfl((int)pfx, 63);
    nc = nc < WCAND ? nc : WCAND;
    for (unsigned s = 0; s < c; ++s) {
      unsigned slot = base + s;
      if (slot < WCAND) cl[w][slot] = cand[cb * SLOTS + s] & 0xFFFFu;
    }
    // same-wave LDS write->read: DS pipe is in-order per wave

    // chunks of 8 candidates, y rows register-resident, online-rescaled softmax
    float me = -3.0e38f, p0 = 0.f, p1 = 0.f, p2 = 0.f;
    f32x4 A0 = {0,0,0,0}, A1 = {0,0,0,0}, A2 = {0,0,0,0};
    for (int bs = 0; bs < nc; bs += 8) {
      const int rem = nc - bs;
      int jq[8];
      f32x4 yv[8];
      float dq[8], uq[8];
      #pragma unroll
      for (int q = 0; q < 8; ++q) {
        int idx = (q < rem) ? bs + q : bs;
        jq[q] = (int)cl[w][idx];
        yv[q] = *reinterpret_cast<const f32x4*>(y + (size_t)jq[q] * DIM + lane * 4);
      }
      #pragma unroll
      for (int q = 0; q < 8; ++q)
        dq[q] = xv[0]*yv[q][0] + xv[1]*yv[q][1] + xv[2]*yv[q][2] + xv[3]*yv[q][3];
      #pragma unroll
      for (int off = 32; off; off >>= 1)
        #pragma unroll
        for (int q = 0; q < 8; ++q) dq[q] += __shfl_xor(dq[q], off);
      #pragma unroll
      for (int q = 0; q < 8; ++q)
        uq[q] = (q < rem) ? 2.0f * dq[q] - bb[jq[q]] : -3.0e38f;

      float cm = uq[0];
      #pragma unroll
      for (int q = 1; q < 8; ++q) cm = fmaxf(cm, uq[q]);
      float nm = fmaxf(me, cm);
      float r0 = exp2fast((me - nm) * c0);
      float r1 = exp2fast((me - nm) * c1);
      float r2 = exp2fast((me - nm) * c2);
      p0 *= r0; p1 *= r1; p2 *= r2;
      A0 *= r0; A1 *= r1; A2 *= r2;
      #pragma unroll
      for (int q = 0; q < 8; ++q) {
        float du = uq[q] - nm;
        float e0 = exp2fast(du * c0);
        float e1 = exp2fast(du * c1);
        float e2 = exp2fast(du * c2);
        p0 += e0; p1 += e1; p2 += e2;
        A0 += e0 * yv[q]; A1 += e1 * yv[q]; A2 += e2 * yv[q];
      }
      me = nm;
    }
    V0 += (sgn / p0) * A0;
    V1 += (sgn / p1) * A1;
    V2 += (sgn / p2) * A2;
  }

  f32x4 vr = (V0 + V1 + V2) * (1.0f / 3.0f);
  *reinterpret_cast<f32x4*>(Vout + (size_t)row * DIM + lane * 4) = vr;

  float s0 = V0[0]*V0[0] + V0[1]*V0[1] + V0[2]*V0[2] + V0[3]*V0[3];
  float s1 = V1[0]*V1[0] + V1[1]*V1[1] + V1[2]*V1[2] + V1[3]*V1[3];
  float s2 = V2[0]*V2[0] + V2[1]*V2[1] + V2[2]*V2[2] + V2[3]*V2[3];
  float sr = vr[0]*vr[0] + vr[1]*vr[1] + vr[2]*vr[2] + vr[3]*vr[3];
  #pragma unroll
  for (int off = 32; off; off >>= 1) {
    s0 += __shfl_xor(s0, off);
    s1 += __shfl_xor(s1, off);
    s2 += __shfl_xor(s2, off);
    sr += __shfl_xor(sr, off);
  }
  if (lane == 0) {
    parts[row]            = sr;
    parts[NPTS + row]     = s0;
    parts[2 * NPTS + row] = s1;
    parts[3 * NPTS + row] = s2;
  }
}

// ---------- reduce_parts ----------
__global__ __launch_bounds__(256) void reduce_parts(
    const float* __restrict__ parts, float* __restrict__ accums)
{
  __shared__ float red[4];
  int tid = threadIdx.x;
  #pragma unroll
  for (int a = 0; a < 4; ++a) {
    float s = 0.f;
    for (int k = tid; k < NPTS; k += 256) s += parts[a * NPTS + k];
    s = blk_sum(s, red);
    if (tid == 0) accums[1 + a] = s;
  }
}

// ---------- K4: finalize ----------
__global__ __launch_bounds__(256) void final_kernel(
    const float* __restrict__ accums, float* __restrict__ out)
{
  float raw  = accums[1] * (1.0f / NPTS);
  float lam2 = raw * (1.0f / DIM) + 1e-8f;
  float lam  = sqrtf(lam2);
  float inv  = 1.0f / lam;
  size_t idx = (size_t)blockIdx.x * 256 + threadIdx.x;
  out[7 + idx] *= inv;
  if (blockIdx.x == 0 && threadIdx.x == 0) {
    float drift = raw / lam2;
    out[0] = drift * (1.0f / DIM);
    out[1] = drift;
    out[2] = raw;
    out[3] = lam;
    out[4] = accums[2] * (1.0f / NPTS);
    out[5] = accums[3] * (1.0f / NPTS);
    out[6] = accums[4] * (1.0f / NPTS);
  }
}

extern "C" void kernel_launch(void* const* d_in, const int* in_sizes, int n_in,
                              void* d_out, int out_size, void* d_ws, size_t ws_size,
                              hipStream_t stream)
{
  (void)in_sizes; (void)n_in; (void)out_size; (void)ws_size;
  const float* x    = (const float*)d_in[0];
  const float* ypos = (const float*)d_in[1];
  const float* yneg = (const float*)d_in[2];
  float* out = (float*)d_out;
  char* ws = (char*)d_ws;

  // ws layout (cnt/cand/M fully rewritten each launch; no zeroing needed):
  // accums 256B | bbp 16K | bbn 16K | parts 64K | M 2M | cnt 2M | cand 25M | xb/ypb/ynb 6M
  float*    accums = (float*)ws;
  float*    bbp    = (float*)(ws + 256);
  float*    bbn    = (float*)(ws + 16640);
  float*    parts  = (float*)(ws + 33024);
  float*    M      = (float*)(ws + 98560);
  unsigned* cnt    = (unsigned*)(ws + 98560 + 2097152);
  unsigned* cand   = (unsigned*)(ws + 98560 + 2 * 2097152);
  u16* xb  = (u16*)(ws + 98560 + 2 * 2097152 + (size_t)2 * TIL * NPTS * SLOTS * 4);
  u16* ypb = xb + (size_t)NPTS * DIM;
  u16* ynb = xb + 2 * (size_t)NPTS * DIM;

  split3_kernel<<<dim3(NPTS / 4, 3), 256, 0, stream>>>(x, ypos, yneg, xb, ypb, ynb, bbp, bbn);
  reduce_ss<<<1, 256, 0, stream>>>(bbp, bbn, accums);
  gemm_kernel<<<dim3(32, 32, 2), 256, 0, stream>>>(xb, ypb, ynb, bbp, bbn, accums,
                                                   M, cnt, cand);
  row_kernel<<<NPTS / 4, 256, 0, stream>>>(M, cnt, cand, bbp, bbn, x, ypos, yneg,
                                           accums, parts, out + 7);
  reduce_parts<<<1, 256, 0, stream>>>(parts, accums);
  final_kernel<<<NPTS, 256, 0, stream>>>(accums, out);
}

// Round 9
// 86.357 us; speedup vs baseline: 1.8922x; 1.2369x over previous
//
#include <hip/hip_runtime.h>

#define NPTS 4096
#define DIM  256
#define TIL  64       // number of 64-wide col tiles
#define WCAND 32      // per-row candidate cap in row_kernel

typedef unsigned short u16;
typedef unsigned long long u64;
typedef __attribute__((ext_vector_type(8))) short bf16x8;
typedef __attribute__((ext_vector_type(4))) float f32x4;
typedef __attribute__((ext_vector_type(4))) unsigned short u16x4;

__device__ __forceinline__ float exp2fast(float x) {
  float r;
  asm("v_exp_f32 %0, %1" : "=v"(r) : "v"(x));
  return r;
}

__device__ __forceinline__ void gload_lds16(const void* g, void* l) {
  __builtin_amdgcn_global_load_lds((const __attribute__((address_space(1))) void*)g,
                                   (__attribute__((address_space(3))) void*)l, 16, 0, 0);
}

__device__ __forceinline__ float blk_sum(float v, float* sh) {
  #pragma unroll
  for (int off = 32; off; off >>= 1) v += __shfl_down(v, off);
  int lane = threadIdx.x & 63, w = threadIdx.x >> 6;
  __syncthreads();
  if (lane == 0) sh[w] = v;
  __syncthreads();
  return sh[0] + sh[1] + sh[2] + sh[3];
}

// ---------- K1: bf16 round + row sumsq for all three inputs ----------
__global__ __launch_bounds__(256) void split3_kernel(
    const float* __restrict__ x, const float* __restrict__ yp, const float* __restrict__ yn,
    u16* __restrict__ xb, u16* __restrict__ ypb, u16* __restrict__ ynb,
    float* __restrict__ bbp, float* __restrict__ bbn)
{
  const float* src; u16* dst; float* bb;
  if      (blockIdx.y == 0) { src = x;  dst = xb;  bb = nullptr; }
  else if (blockIdx.y == 1) { src = yp; dst = ypb; bb = bbp; }
  else                      { src = yn; dst = ynb; bb = bbn; }

  int lane = threadIdx.x & 63;
  int wave = threadIdx.x >> 6;
  int row  = blockIdx.x * 4 + wave;
  const float4 v = *reinterpret_cast<const float4*>(src + (size_t)row * DIM + lane * 4);
  float xs[4] = {v.x, v.y, v.z, v.w};
  u16x4 h;
  float ss = 0.f;
  #pragma unroll
  for (int e = 0; e < 4; ++e) {
    unsigned b = __float_as_uint(xs[e]);
    h[e] = (u16)((b + 0x7fffu + ((b >> 16) & 1u)) >> 16);   // bf16 RTNE
    ss += xs[e] * xs[e];
  }
  *reinterpret_cast<u16x4*>(dst + (size_t)row * DIM + lane * 4) = h;
  if (bb) {
    #pragma unroll
    for (int off = 32; off; off >>= 1) ss += __shfl_down(ss, off);
    if (lane == 0) bb[row] = ss;
  }
}

// ---------- reduce_ss: accums[0] = sum(bbp) + sum(bbn) ----------
__global__ __launch_bounds__(256) void reduce_ss(
    const float* __restrict__ bbp, const float* __restrict__ bbn, float* __restrict__ accums)
{
  __shared__ float red[4];
  int tid = threadIdx.x;
  float s = 0.f;
  for (int k = tid; k < NPTS; k += 256) s += bbp[k] + bbn[k];
  s = blk_sum(s, red);
  if (tid == 0) accums[0] = s;
}

// ---------- K2: bf16 GEMM 128x128, BK=32 dbuf, counted vmcnt, mask epilogue ----------
__global__ __launch_bounds__(256, 4) void gemm_kernel(
    const u16* __restrict__ Xb, const u16* __restrict__ Ypb, const u16* __restrict__ Ynb,
    const float* __restrict__ bbp, const float* __restrict__ bbn,
    const float* __restrict__ accums,
    float* __restrict__ M, u64* __restrict__ Kmask)
{
  __shared__ u16 Ah[2][128 * 32];
  __shared__ u16 Bh[2][128 * 32];

  const int side = blockIdx.z;
  const u16* Yb = side ? Ynb : Ypb;
  const float* bbv = side ? bbn : bbp;

  const int tid  = threadIdx.x;
  const int lane = tid & 63;
  const int wave = tid >> 6;
  const int wm = wave >> 1, wn = wave & 1;
  const int l15 = lane & 15, lhi = lane >> 4;

  const int rf = blockIdx.x * 128;   // x rows
  const int cf = blockIdx.y * 128;   // y rows (cols of S)
  const int til = blockIdx.y * 2 + wn;

  // staging coords: thread covers 2 chunk-ids per array; cid -> (row, phys chunk)
  // source chunk pre-swizzled (gc = pc ^ (r&3)) so reads XOR-deswizzle
  const int r0  = tid >> 2;            // cid = tid
  const int pc0 = tid & 3;
  const int r1  = (tid + 256) >> 2;    // cid = tid + 256
  const int pc1 = tid & 3;

  f32x4 acc[4][4] = {};

  // prologue: stage ks=0 into buffer 0 (4 loads/thread)
  {
    int gc0 = pc0 ^ (r0 & 3), gc1 = pc1 ^ (r1 & 3);
    gload_lds16(Xb + (size_t)(rf + r0) * DIM + gc0 * 8, Ah[0] + r0 * 32 + pc0 * 8);
    gload_lds16(Yb + (size_t)(cf + r0) * DIM + gc0 * 8, Bh[0] + r0 * 32 + pc0 * 8);
    gload_lds16(Xb + (size_t)(rf + r1) * DIM + gc1 * 8, Ah[0] + r1 * 32 + pc1 * 8);
    gload_lds16(Yb + (size_t)(cf + r1) * DIM + gc1 * 8, Bh[0] + r1 * 32 + pc1 * 8);
  }

  #pragma unroll 2
  for (int ks = 0; ks < 8; ++ks) {
    const int cur = ks & 1;
    // drain only this step's 4 loads; next step's stay in flight
    if (ks < 7) asm volatile("s_waitcnt vmcnt(4)" ::: "memory");
    else        asm volatile("s_waitcnt vmcnt(0)" ::: "memory");
    __builtin_amdgcn_s_barrier();

    if (ks < 7) {
      int ko = (ks + 1) * 32;
      int gc0 = pc0 ^ (r0 & 3), gc1 = pc1 ^ (r1 & 3);
      gload_lds16(Xb + (size_t)(rf + r0) * DIM + ko + gc0 * 8, Ah[cur ^ 1] + r0 * 32 + pc0 * 8);
      gload_lds16(Yb + (size_t)(cf + r0) * DIM + ko + gc0 * 8, Bh[cur ^ 1] + r0 * 32 + pc0 * 8);
      gload_lds16(Xb + (size_t)(rf + r1) * DIM + ko + gc1 * 8, Ah[cur ^ 1] + r1 * 32 + pc1 * 8);
      gload_lds16(Yb + (size_t)(cf + r1) * DIM + ko + gc1 * 8, Bh[cur ^ 1] + r1 * 32 + pc1 * 8);
    }

    bf16x8 a[4], b[4];
    #pragma unroll
    for (int mi = 0; mi < 4; ++mi) {
      int R = wm * 64 + mi * 16 + l15;
      a[mi] = *reinterpret_cast<const bf16x8*>(Ah[cur] + R * 32 + ((lhi ^ (R & 3)) * 8));
    }
    #pragma unroll
    for (int ni = 0; ni < 4; ++ni) {
      int R = wn * 64 + ni * 16 + l15;
      b[ni] = *reinterpret_cast<const bf16x8*>(Bh[cur] + R * 32 + ((lhi ^ (R & 3)) * 8));
    }
    #pragma unroll
    for (int mi = 0; mi < 4; ++mi)
      #pragma unroll
      for (int ni = 0; ni < 4; ++ni)
        acc[mi][ni] = __builtin_amdgcn_mfma_f32_16x16x32_bf16(a[mi], b[ni], acc[mi][ni], 0, 0, 0);
  }

  // ---- epilogue: u = 2*acc - bb[col]; per-(row,tile) max + 64-bit keep mask ----
  const float scalesq = accums[0] * (1.0f / (2.0f * NPTS * DIM)) + 1e-8f;
  const float thrP = 30.0f * scalesq * 0.2f + 2.5f * scalesq + 0.5f;

  float bbc[4];
  #pragma unroll
  for (int ni = 0; ni < 4; ++ni) bbc[ni] = bbv[cf + wn * 64 + ni * 16 + l15];

  #pragma unroll
  for (int mi = 0; mi < 4; ++mi)
    #pragma unroll
    for (int r = 0; r < 4; ++r) {
      float uv[4];
      float mx = -3.0e38f;
      #pragma unroll
      for (int ni = 0; ni < 4; ++ni) {
        uv[ni] = 2.0f * acc[mi][ni][r] - bbc[ni];
        mx = fmaxf(mx, uv[ni]);
      }
      #pragma unroll
      for (int off = 1; off < 16; off <<= 1) mx = fmaxf(mx, __shfl_xor(mx, off));
      const float cut = mx - thrP;

      u64 bal[4];
      #pragma unroll
      for (int ni = 0; ni < 4; ++ni) bal[ni] = __ballot(uv[ni] > cut);

      // assemble this lhi-row's 64-col mask: bits [ni*16+15 : ni*16] from slice lhi
      u64 mask = 0;
      #pragma unroll
      for (int ni = 0; ni < 4; ++ni)
        mask |= ((bal[ni] >> (lhi * 16)) & 0xFFFFull) << (ni * 16);

      const int rowG = rf + wm * 64 + mi * 16 + lhi * 4 + r;
      if (l15 == 0) {
        Kmask[((size_t)side * TIL + til) * NPTS + rowG] = mask;
        M[((size_t)side * NPTS + rowG) * TIL + til] = mx;
      }
    }
}

// ---------- K3: wave-per-row; mask harvest + register candidates ----------
__global__ __launch_bounds__(256) void row_kernel(
    const float* __restrict__ M, const u64* __restrict__ Kmask,
    const float* __restrict__ bbp, const float* __restrict__ bbn,
    const float* __restrict__ x,
    const float* __restrict__ ypos, const float* __restrict__ yneg,
    const float* __restrict__ accums, float* __restrict__ parts,
    float* __restrict__ Vout)
{
  __shared__ unsigned cl[4][WCAND];

  const int tid  = threadIdx.x;
  const int lane = tid & 63;
  const int w    = tid >> 6;
  const int row  = blockIdx.x * 4 + w;

  const float scalesq = accums[0] * (1.0f / (2.0f * NPTS * DIM)) + 1e-8f;
  const float L2E = 1.4426950408889634f;
  const float c0 = L2E / (scalesq * 0.02f);
  const float c1 = L2E / (scalesq * 0.05f);
  const float c2 = L2E / (scalesq * 0.2f);
  const float thrP = 30.0f * scalesq * 0.2f + 2.5f * scalesq + 0.5f;

  const f32x4 xv = *reinterpret_cast<const f32x4*>(x + (size_t)row * DIM + lane * 4);

  f32x4 V0 = {0,0,0,0}, V1 = {0,0,0,0}, V2 = {0,0,0,0};

  for (int side = 0; side < 2; ++side) {
    const float* bb = side ? bbn : bbp;
    const float* y  = side ? yneg : ypos;
    const float sgn = side ? -1.f : 1.f;

    // lane t owns tile t: global row max
    float Mv = M[((size_t)side * NPTS + row) * TIL + lane];
    float g = Mv;
    #pragma unroll
    for (int off = 32; off; off >>= 1) g = fmaxf(g, __shfl_xor(g, off));
    const float cut = g - thrP;

    // harvest candidates from kept tiles' masks (few tiles)
    u64 mm = __ballot(Mv > cut);
    int nc = 0;
    while (mm) {
      int t = __ffsll((long long)mm) - 1;
      mm &= mm - 1;
      u64 mask = Kmask[((size_t)side * TIL + t) * NPTS + row];   // uniform broadcast
      bool keep = (mask >> lane) & 1ull;
      int rank = __popcll(mask & ((1ull << lane) - 1ull));
      if (keep && nc + rank < WCAND) cl[w][nc + rank] = t * 64 + lane;
      nc += __popcll(mask);
    }
    nc = nc < WCAND ? nc : WCAND;
    // same-wave LDS write->read; DS pipe in-order per wave

    // chunks of 8 candidates, y rows register-resident, online-rescaled softmax
    float me = -3.0e38f, p0 = 0.f, p1 = 0.f, p2 = 0.f;
    f32x4 A0 = {0,0,0,0}, A1 = {0,0,0,0}, A2 = {0,0,0,0};
    for (int bs = 0; bs < nc; bs += 8) {
      const int rem = nc - bs;
      int jq[8];
      f32x4 yv[8];
      float dq[8], uq[8];
      #pragma unroll
      for (int q = 0; q < 8; ++q) {
        int idx = (q < rem) ? bs + q : bs;
        jq[q] = (int)cl[w][idx];
        yv[q] = *reinterpret_cast<const f32x4*>(y + (size_t)jq[q] * DIM + lane * 4);
      }
      #pragma unroll
      for (int q = 0; q < 8; ++q)
        dq[q] = xv[0]*yv[q][0] + xv[1]*yv[q][1] + xv[2]*yv[q][2] + xv[3]*yv[q][3];
      #pragma unroll
      for (int off = 32; off; off >>= 1)
        #pragma unroll
        for (int q = 0; q < 8; ++q) dq[q] += __shfl_xor(dq[q], off);
      #pragma unroll
      for (int q = 0; q < 8; ++q)
        uq[q] = (q < rem) ? 2.0f * dq[q] - bb[jq[q]] : -3.0e38f;

      float cm = uq[0];
      #pragma unroll
      for (int q = 1; q < 8; ++q) cm = fmaxf(cm, uq[q]);
      float nm = fmaxf(me, cm);
      float s0 = exp2fast((me - nm) * c0);
      float s1 = exp2fast((me - nm) * c1);
      float s2 = exp2fast((me - nm) * c2);
      p0 *= s0; p1 *= s1; p2 *= s2;
      A0 *= s0; A1 *= s1; A2 *= s2;
      #pragma unroll
      for (int q = 0; q < 8; ++q) {
        float du = uq[q] - nm;
        float e0 = exp2fast(du * c0);
        float e1 = exp2fast(du * c1);
        float e2 = exp2fast(du * c2);
        p0 += e0; p1 += e1; p2 += e2;
        A0 += e0 * yv[q]; A1 += e1 * yv[q]; A2 += e2 * yv[q];
      }
      me = nm;
    }
    V0 += (sgn / p0) * A0;
    V1 += (sgn / p1) * A1;
    V2 += (sgn / p2) * A2;
  }

  f32x4 vr = (V0 + V1 + V2) * (1.0f / 3.0f);
  *reinterpret_cast<f32x4*>(Vout + (size_t)row * DIM + lane * 4) = vr;

  float s0 = V0[0]*V0[0] + V0[1]*V0[1] + V0[2]*V0[2] + V0[3]*V0[3];
  float s1 = V1[0]*V1[0] + V1[1]*V1[1] + V1[2]*V1[2] + V1[3]*V1[3];
  float s2 = V2[0]*V2[0] + V2[1]*V2[1] + V2[2]*V2[2] + V2[3]*V2[3];
  float sr = vr[0]*vr[0] + vr[1]*vr[1] + vr[2]*vr[2] + vr[3]*vr[3];
  #pragma unroll
  for (int off = 32; off; off >>= 1) {
    s0 += __shfl_xor(s0, off);
    s1 += __shfl_xor(s1, off);
    s2 += __shfl_xor(s2, off);
    sr += __shfl_xor(sr, off);
  }
  if (lane == 0) {
    parts[row]            = sr;
    parts[NPTS + row]     = s0;
    parts[2 * NPTS + row] = s1;
    parts[3 * NPTS + row] = s2;
  }
}

// ---------- reduce_parts ----------
__global__ __launch_bounds__(256) void reduce_parts(
    const float* __restrict__ parts, float* __restrict__ accums)
{
  __shared__ float red[4];
  int tid = threadIdx.x;
  #pragma unroll
  for (int a = 0; a < 4; ++a) {
    float s = 0.f;
    for (int k = tid; k < NPTS; k += 256) s += parts[a * NPTS + k];
    s = blk_sum(s, red);
    if (tid == 0) accums[1 + a] = s;
  }
}

// ---------- K4: finalize ----------
__global__ __launch_bounds__(256) void final_kernel(
    const float* __restrict__ accums, float* __restrict__ out)
{
  float raw  = accums[1] * (1.0f / NPTS);
  float lam2 = raw * (1.0f / DIM) + 1e-8f;
  float lam  = sqrtf(lam2);
  float inv  = 1.0f / lam;
  size_t idx = (size_t)blockIdx.x * 256 + threadIdx.x;
  out[7 + idx] *= inv;
  if (blockIdx.x == 0 && threadIdx.x == 0) {
    float drift = raw / lam2;
    out[0] = drift * (1.0f / DIM);
    out[1] = drift;
    out[2] = raw;
    out[3] = lam;
    out[4] = accums[2] * (1.0f / NPTS);
    out[5] = accums[3] * (1.0f / NPTS);
    out[6] = accums[4] * (1.0f / NPTS);
  }
}

extern "C" void kernel_launch(void* const* d_in, const int* in_sizes, int n_in,
                              void* d_out, int out_size, void* d_ws, size_t ws_size,
                              hipStream_t stream)
{
  (void)in_sizes; (void)n_in; (void)out_size; (void)ws_size;
  const float* x    = (const float*)d_in[0];
  const float* ypos = (const float*)d_in[1];
  const float* yneg = (const float*)d_in[2];
  float* out = (float*)d_out;
  char* ws = (char*)d_ws;

  // ws layout (M/Kmask fully rewritten each launch; no zeroing needed):
  // accums 256B | bbp 16K | bbn 16K | parts 64K | M 2M | Kmask 4M | xb/ypb/ynb 6M
  float* accums = (float*)ws;
  float* bbp    = (float*)(ws + 256);
  float* bbn    = (float*)(ws + 16640);
  float* parts  = (float*)(ws + 33024);
  float* M      = (float*)(ws + 98560);
  u64*   Kmask  = (u64*)(ws + 98560 + 2097152);
  u16* xb  = (u16*)(ws + 98560 + 2097152 + 4194304);
  u16* ypb = xb + (size_t)NPTS * DIM;
  u16* ynb = xb + 2 * (size_t)NPTS * DIM;

  split3_kernel<<<dim3(NPTS / 4, 3), 256, 0, stream>>>(x, ypos, yneg, xb, ypb, ynb, bbp, bbn);
  reduce_ss<<<1, 256, 0, stream>>>(bbp, bbn, accums);
  gemm_kernel<<<dim3(32, 32, 2), 256, 0, stream>>>(xb, ypb, ynb, bbp, bbn, accums, M, Kmask);
  row_kernel<<<NPTS / 4, 256, 0, stream>>>(M, Kmask, bbp, bbn, x, ypos, yneg,
                                           accums, parts, out + 7);
  reduce_parts<<<1, 256, 0, stream>>>(parts, accums);
  final_kernel<<<NPTS, 256, 0, stream>>>(accums, out);
}

// Round 10
// 83.349 us; speedup vs baseline: 1.9605x; 1.0361x over previous
//
#include <hip/hip_runtime.h>

#define NPTS 4096
#define DIM  256
#define TIL  64       // number of 64-wide col tiles
#define WCAND 32      // per-row candidate cap in row_kernel

typedef unsigned short u16;
typedef unsigned long long u64;
typedef __attribute__((ext_vector_type(8))) short bf16x8;
typedef __attribute__((ext_vector_type(4))) float f32x4;
typedef __attribute__((ext_vector_type(4))) unsigned short u16x4;

__device__ __forceinline__ float exp2fast(float x) {
  float r;
  asm("v_exp_f32 %0, %1" : "=v"(r) : "v"(x));
  return r;
}

__device__ __forceinline__ void gload_lds16(const void* g, void* l) {
  __builtin_amdgcn_global_load_lds((const __attribute__((address_space(1))) void*)g,
                                   (__attribute__((address_space(3))) void*)l, 16, 0, 0);
}

__device__ __forceinline__ float blk_sum(float v, float* sh) {
  #pragma unroll
  for (int off = 32; off; off >>= 1) v += __shfl_down(v, off);
  int lane = threadIdx.x & 63, w = threadIdx.x >> 6;
  __syncthreads();
  if (lane == 0) sh[w] = v;
  __syncthreads();
  return sh[0] + sh[1] + sh[2] + sh[3];
}

// per-block redundant scalesq: reduces bbp+bbn (8192 floats, L2-hot)
__device__ __forceinline__ float block_scalesq(
    const float* __restrict__ bbp, const float* __restrict__ bbn, float* red, int tid) {
  float s = 0.f;
  #pragma unroll
  for (int q = 0; q < 4; ++q) {
    f32x4 a = *reinterpret_cast<const f32x4*>(bbp + (q * 256 + tid) * 4);
    f32x4 b = *reinterpret_cast<const f32x4*>(bbn + (q * 256 + tid) * 4);
    s += a[0] + a[1] + a[2] + a[3] + b[0] + b[1] + b[2] + b[3];
  }
  float tot = blk_sum(s, red);
  return tot * (1.0f / (2.0f * NPTS * DIM)) + 1e-8f;
}

// ---------- K1: bf16 round + row sumsq for all three inputs ----------
__global__ __launch_bounds__(256) void split3_kernel(
    const float* __restrict__ x, const float* __restrict__ yp, const float* __restrict__ yn,
    u16* __restrict__ xb, u16* __restrict__ ypb, u16* __restrict__ ynb,
    float* __restrict__ bbp, float* __restrict__ bbn)
{
  const float* src; u16* dst; float* bb;
  if      (blockIdx.y == 0) { src = x;  dst = xb;  bb = nullptr; }
  else if (blockIdx.y == 1) { src = yp; dst = ypb; bb = bbp; }
  else                      { src = yn; dst = ynb; bb = bbn; }

  int lane = threadIdx.x & 63;
  int wave = threadIdx.x >> 6;
  int row  = blockIdx.x * 4 + wave;
  const float4 v = *reinterpret_cast<const float4*>(src + (size_t)row * DIM + lane * 4);
  float xs[4] = {v.x, v.y, v.z, v.w};
  u16x4 h;
  float ss = 0.f;
  #pragma unroll
  for (int e = 0; e < 4; ++e) {
    unsigned b = __float_as_uint(xs[e]);
    h[e] = (u16)((b + 0x7fffu + ((b >> 16) & 1u)) >> 16);   // bf16 RTNE
    ss += xs[e] * xs[e];
  }
  *reinterpret_cast<u16x4*>(dst + (size_t)row * DIM + lane * 4) = h;
  if (bb) {
    #pragma unroll
    for (int off = 32; off; off >>= 1) ss += __shfl_down(ss, off);
    if (lane == 0) bb[row] = ss;
  }
}

// ---------- K2: bf16 GEMM 128x128, 3-buffer rotation, counted vmcnt, mask epilogue ----------
__global__ __launch_bounds__(256, 3) void gemm_kernel(
    const u16* __restrict__ Xb, const u16* __restrict__ Ypb, const u16* __restrict__ Ynb,
    const float* __restrict__ bbp, const float* __restrict__ bbn,
    float* __restrict__ M, u64* __restrict__ Kmask)
{
  __shared__ u16 Ah[3][128 * 32];
  __shared__ u16 Bh[3][128 * 32];
  __shared__ float red[4];

  const int tid  = threadIdx.x;

  // T1: XCD-bijective swizzle (2048 blocks, 2048 % 8 == 0)
  const unsigned lid = blockIdx.x + (blockIdx.y << 5) + (blockIdx.z << 10);
  const unsigned swz = (lid & 7) * 256 + (lid >> 3);
  const int bx = swz & 31, by = (swz >> 5) & 31, side = (int)(swz >> 10);

  const u16* Yb = side ? Ynb : Ypb;
  const float* bbv = side ? bbn : bbp;

  const float scalesq = block_scalesq(bbp, bbn, red, tid);

  const int lane = tid & 63;
  const int wave = tid >> 6;
  const int wm = wave >> 1, wn = wave & 1;
  const int l15 = lane & 15, lhi = lane >> 4;

  const int rf = bx * 128;           // x rows
  const int cf = by * 128;           // y rows (cols of S)
  const int til = by * 2 + wn;

  // staging coords: thread covers 2 chunk-ids; cid -> (row, phys chunk)
  // source chunk pre-swizzled (gc = pc ^ (r&3)) so reads XOR-deswizzle
  const int r0  = tid >> 2;
  const int r1  = (tid + 256) >> 2;
  const int pc  = tid & 3;
  const int gc0 = pc ^ (r0 & 3);
  const int gc1 = pc ^ (r1 & 3);

  f32x4 acc[4][4] = {};

#define STAGE(KS, BUF)                                                                    \
  do {                                                                                    \
    int ko_ = (KS) * 32;                                                                  \
    gload_lds16(Xb + (size_t)(rf + r0) * DIM + ko_ + gc0 * 8, Ah[BUF] + r0 * 32 + pc * 8);\
    gload_lds16(Yb + (size_t)(cf + r0) * DIM + ko_ + gc0 * 8, Bh[BUF] + r0 * 32 + pc * 8);\
    gload_lds16(Xb + (size_t)(rf + r1) * DIM + ko_ + gc1 * 8, Ah[BUF] + r1 * 32 + pc * 8);\
    gload_lds16(Yb + (size_t)(cf + r1) * DIM + ko_ + gc1 * 8, Bh[BUF] + r1 * 32 + pc * 8);\
  } while (0)

  // prologue: two K-steps in flight
  STAGE(0, 0);
  STAGE(1, 1);

  #pragma unroll 1
  for (int ks = 0; ks < 8; ++ks) {
    const int cur = ks % 3;
    // at this point outstanding = stage(ks+1)'s 4 loads; stage(ks)'s are older
    if (ks < 7) asm volatile("s_waitcnt vmcnt(4)" ::: "memory");
    else        asm volatile("s_waitcnt vmcnt(0)" ::: "memory");
    __builtin_amdgcn_s_barrier();
    __builtin_amdgcn_sched_barrier(0);

    // stage 2 ahead; target buffer was read at ks-1, ordered by the barrier above
    if (ks < 6) STAGE(ks + 2, (ks + 2) % 3);

    bf16x8 a[4], b[4];
    #pragma unroll
    for (int mi = 0; mi < 4; ++mi) {
      int R = wm * 64 + mi * 16 + l15;
      a[mi] = *reinterpret_cast<const bf16x8*>(Ah[cur] + R * 32 + ((lhi ^ (R & 3)) * 8));
    }
    #pragma unroll
    for (int ni = 0; ni < 4; ++ni) {
      int R = wn * 64 + ni * 16 + l15;
      b[ni] = *reinterpret_cast<const bf16x8*>(Bh[cur] + R * 32 + ((lhi ^ (R & 3)) * 8));
    }
    #pragma unroll
    for (int mi = 0; mi < 4; ++mi)
      #pragma unroll
      for (int ni = 0; ni < 4; ++ni)
        acc[mi][ni] = __builtin_amdgcn_mfma_f32_16x16x32_bf16(a[mi], b[ni], acc[mi][ni], 0, 0, 0);
  }
#undef STAGE

  // ---- epilogue: u = 2*acc - bb[col]; per-(row,tile) max + 64-bit keep mask ----
  const float thrP = 30.0f * scalesq * 0.2f + 2.5f * scalesq + 0.5f;

  float bbc[4];
  #pragma unroll
  for (int ni = 0; ni < 4; ++ni) bbc[ni] = bbv[cf + wn * 64 + ni * 16 + l15];

  #pragma unroll
  for (int mi = 0; mi < 4; ++mi)
    #pragma unroll
    for (int r = 0; r < 4; ++r) {
      float uv[4];
      float mx = -3.0e38f;
      #pragma unroll
      for (int ni = 0; ni < 4; ++ni) {
        uv[ni] = 2.0f * acc[mi][ni][r] - bbc[ni];
        mx = fmaxf(mx, uv[ni]);
      }
      #pragma unroll
      for (int off = 1; off < 16; off <<= 1) mx = fmaxf(mx, __shfl_xor(mx, off));
      const float cut = mx - thrP;

      u64 bal[4];
      #pragma unroll
      for (int ni = 0; ni < 4; ++ni) bal[ni] = __ballot(uv[ni] > cut);

      u64 mask = 0;
      #pragma unroll
      for (int ni = 0; ni < 4; ++ni)
        mask |= ((bal[ni] >> (lhi * 16)) & 0xFFFFull) << (ni * 16);

      const int rowG = rf + wm * 64 + mi * 16 + lhi * 4 + r;
      if (l15 == 0) {
        Kmask[((size_t)side * TIL + til) * NPTS + rowG] = mask;
        M[((size_t)side * NPTS + rowG) * TIL + til] = mx;
      }
    }
}

// ---------- K3: wave-per-row; mask harvest + register candidates ----------
__global__ __launch_bounds__(256) void row_kernel(
    const float* __restrict__ M, const u64* __restrict__ Kmask,
    const float* __restrict__ bbp, const float* __restrict__ bbn,
    const float* __restrict__ x,
    const float* __restrict__ ypos, const float* __restrict__ yneg,
    float* __restrict__ parts, float* __restrict__ Vout)
{
  __shared__ unsigned cl[4][WCAND];
  __shared__ float red[4];

  const int tid  = threadIdx.x;
  const int lane = tid & 63;
  const int w    = tid >> 6;
  const int row  = blockIdx.x * 4 + w;

  const float scalesq = block_scalesq(bbp, bbn, red, tid);
  const float L2E = 1.4426950408889634f;
  const float c0 = L2E / (scalesq * 0.02f);
  const float c1 = L2E / (scalesq * 0.05f);
  const float c2 = L2E / (scalesq * 0.2f);
  const float thrP = 30.0f * scalesq * 0.2f + 2.5f * scalesq + 0.5f;

  const f32x4 xv = *reinterpret_cast<const f32x4*>(x + (size_t)row * DIM + lane * 4);

  f32x4 V0 = {0,0,0,0}, V1 = {0,0,0,0}, V2 = {0,0,0,0};

  for (int side = 0; side < 2; ++side) {
    const float* bb = side ? bbn : bbp;
    const float* y  = side ? yneg : ypos;
    const float sgn = side ? -1.f : 1.f;

    // lane t owns tile t: global row max
    float Mv = M[((size_t)side * NPTS + row) * TIL + lane];
    float g = Mv;
    #pragma unroll
    for (int off = 32; off; off >>= 1) g = fmaxf(g, __shfl_xor(g, off));
    const float cut = g - thrP;

    // harvest candidates from kept tiles' masks
    u64 mm = __ballot(Mv > cut);
    int nc = 0;
    while (mm) {
      int t = __ffsll((long long)mm) - 1;
      mm &= mm - 1;
      u64 mask = Kmask[((size_t)side * TIL + t) * NPTS + row];   // uniform broadcast
      bool keep = (mask >> lane) & 1ull;
      int rank = __popcll(mask & ((1ull << lane) - 1ull));
      if (keep && nc + rank < WCAND) cl[w][nc + rank] = t * 64 + lane;
      nc += __popcll(mask);
    }
    nc = nc < WCAND ? nc : WCAND;
    // same-wave LDS write->read; DS pipe in-order per wave

    // chunks of 8 candidates, y rows register-resident, online-rescaled softmax
    float me = -3.0e38f, p0 = 0.f, p1 = 0.f, p2 = 0.f;
    f32x4 A0 = {0,0,0,0}, A1 = {0,0,0,0}, A2 = {0,0,0,0};
    for (int bs = 0; bs < nc; bs += 8) {
      const int rem = nc - bs;
      int jq[8];
      f32x4 yv[8];
      float dq[8], uq[8];
      #pragma unroll
      for (int q = 0; q < 8; ++q) {
        int idx = (q < rem) ? bs + q : bs;
        jq[q] = (int)cl[w][idx];
        yv[q] = *reinterpret_cast<const f32x4*>(y + (size_t)jq[q] * DIM + lane * 4);
      }
      #pragma unroll
      for (int q = 0; q < 8; ++q)
        dq[q] = xv[0]*yv[q][0] + xv[1]*yv[q][1] + xv[2]*yv[q][2] + xv[3]*yv[q][3];
      #pragma unroll
      for (int off = 32; off; off >>= 1)
        #pragma unroll
        for (int q = 0; q < 8; ++q) dq[q] += __shfl_xor(dq[q], off);
      #pragma unroll
      for (int q = 0; q < 8; ++q)
        uq[q] = (q < rem) ? 2.0f * dq[q] - bb[jq[q]] : -3.0e38f;

      float cm = uq[0];
      #pragma unroll
      for (int q = 1; q < 8; ++q) cm = fmaxf(cm, uq[q]);
      float nm = fmaxf(me, cm);
      float s0 = exp2fast((me - nm) * c0);
      float s1 = exp2fast((me - nm) * c1);
      float s2 = exp2fast((me - nm) * c2);
      p0 *= s0; p1 *= s1; p2 *= s2;
      A0 *= s0; A1 *= s1; A2 *= s2;
      #pragma unroll
      for (int q = 0; q < 8; ++q) {
        float du = uq[q] - nm;
        float e0 = exp2fast(du * c0);
        float e1 = exp2fast(du * c1);
        float e2 = exp2fast(du * c2);
        p0 += e0; p1 += e1; p2 += e2;
        A0 += e0 * yv[q]; A1 += e1 * yv[q]; A2 += e2 * yv[q];
      }
      me = nm;
    }
    V0 += (sgn / p0) * A0;
    V1 += (sgn / p1) * A1;
    V2 += (sgn / p2) * A2;
  }

  f32x4 vr = (V0 + V1 + V2) * (1.0f / 3.0f);
  *reinterpret_cast<f32x4*>(Vout + (size_t)row * DIM + lane * 4) = vr;

  float s0 = V0[0]*V0[0] + V0[1]*V0[1] + V0[2]*V0[2] + V0[3]*V0[3];
  float s1 = V1[0]*V1[0] + V1[1]*V1[1] + V1[2]*V1[2] + V1[3]*V1[3];
  float s2 = V2[0]*V2[0] + V2[1]*V2[1] + V2[2]*V2[2] + V2[3]*V2[3];
  float sr = vr[0]*vr[0] + vr[1]*vr[1] + vr[2]*vr[2] + vr[3]*vr[3];
  #pragma unroll
  for (int off = 32; off; off >>= 1) {
    s0 += __shfl_xor(s0, off);
    s1 += __shfl_xor(s1, off);
    s2 += __shfl_xor(s2, off);
    sr += __shfl_xor(sr, off);
  }
  if (lane == 0) {
    parts[row]            = sr;
    parts[NPTS + row]     = s0;
    parts[2 * NPTS + row] = s1;
    parts[3 * NPTS + row] = s2;
  }
}

// ---------- K4: fused reduce + finalize + V scale ----------
__global__ __launch_bounds__(256) void final_kernel(
    const float* __restrict__ parts, float* __restrict__ out)
{
  __shared__ float red[4];
  const int tid = threadIdx.x;

  float s = 0.f;
  for (int k = tid; k < NPTS; k += 256) s += parts[k];
  float raw = blk_sum(s, red) * (1.0f / NPTS);
  float lam2 = raw * (1.0f / DIM) + 1e-8f;
  float lam  = sqrtf(lam2);
  float inv  = 1.0f / lam;

  int idx = blockIdx.x * 256 + tid;
  out[7 + idx] *= inv;

  if (blockIdx.x == 0) {
    #pragma unroll
    for (int a = 1; a <= 3; ++a) {
      float t = 0.f;
      for (int k = tid; k < NPTS; k += 256) t += parts[a * NPTS + k];
      t = blk_sum(t, red);
      if (tid == 0) out[3 + a] = t * (1.0f / NPTS);
    }
    if (tid == 0) {
      float drift = raw / lam2;
      out[0] = drift * (1.0f / DIM);
      out[1] = drift;
      out[2] = raw;
      out[3] = lam;
    }
  }
}

extern "C" void kernel_launch(void* const* d_in, const int* in_sizes, int n_in,
                              void* d_out, int out_size, void* d_ws, size_t ws_size,
                              hipStream_t stream)
{
  (void)in_sizes; (void)n_in; (void)out_size; (void)ws_size;
  const float* x    = (const float*)d_in[0];
  const float* ypos = (const float*)d_in[1];
  const float* yneg = (const float*)d_in[2];
  float* out = (float*)d_out;
  char* ws = (char*)d_ws;

  // ws layout (M/Kmask fully rewritten each launch; no zeroing needed):
  // bbp 16K | bbn 16K | parts 64K | M 2M | Kmask 4M | xb/ypb/ynb 6M
  float* bbp   = (float*)ws;
  float* bbn   = (float*)(ws + 16384);
  float* parts = (float*)(ws + 32768);
  float* M     = (float*)(ws + 98304);
  u64*   Kmask = (u64*)(ws + 98304 + 2097152);
  u16* xb  = (u16*)(ws + 98304 + 2097152 + 4194304);
  u16* ypb = xb + (size_t)NPTS * DIM;
  u16* ynb = xb + 2 * (size_t)NPTS * DIM;

  split3_kernel<<<dim3(NPTS / 4, 3), 256, 0, stream>>>(x, ypos, yneg, xb, ypb, ynb, bbp, bbn);
  gemm_kernel<<<dim3(32, 32, 2), 256, 0, stream>>>(xb, ypb, ynb, bbp, bbn, M, Kmask);
  row_kernel<<<NPTS / 4, 256, 0, stream>>>(M, Kmask, bbp, bbn, x, ypos, yneg,
                                           parts, out + 7);
  final_kernel<<<NPTS, 256, 0, stream>>>(parts, out);
}